// Round 8
// baseline (728.288 us; speedup 1.0000x reference)
//
#include <hip/hip_runtime.h>
#include <math.h>

// Problem constants (match reference)
constexpr int T1N  = 30000;
constexpr int T2N  = 8192;
constexpr int FIN  = 512;
constexpr int FHID = 256;
constexpr int FOUT = 20;
constexpr int NPAD = 32;    // z / mean_z column stride (20 padded to 32)

typedef short bf16x8 __attribute__((ext_vector_type(8)));
typedef short bf16x4 __attribute__((ext_vector_type(4)));
typedef float f32x4  __attribute__((ext_vector_type(4)));

__device__ __forceinline__ short f2bf(float f) {
    unsigned u = __float_as_uint(f);
    u += 0x7fff + ((u >> 16) & 1);     // RNE; inputs are finite normals
    return (short)(u >> 16);
}
__device__ __forceinline__ float bf2f(short s) {
    return __uint_as_float(((unsigned)(unsigned short)s) << 16);
}

__device__ __forceinline__ void gload16(const void* g, void* l) {
    __builtin_amdgcn_global_load_lds(
        (const __attribute__((address_space(1))) void*)g,
        (__attribute__((address_space(3))) void*)l, 16, 0, 0);
}

// ---------------------------------------------------------------------------
// CSR build (both graphs in merged dispatches)
// ---------------------------------------------------------------------------
__global__ void count_both(const int* __restrict__ dst1, const int* __restrict__ dst2,
        int* __restrict__ cnt1, int* __restrict__ cnt2, int E1, int E2) {
    int i = blockIdx.x * blockDim.x + threadIdx.x;
    int stride = gridDim.x * blockDim.x;
    int tot = E1 + E2;
    for (; i < tot; i += stride) {
        if (i < E1) atomicAdd(&cnt1[dst1[i]], 1);
        else        atomicAdd(&cnt2[dst2[i - E1]], 1);
    }
}

// grid=2: block 0 scans graph1, block 1 scans graph2. int4 (4096/chunk).
__global__ __launch_bounds__(1024) void scan_both(
        const int* __restrict__ cnt1, int* __restrict__ rs1, int* __restrict__ cur1,
        const int* __restrict__ cnt2, int* __restrict__ rs2, int* __restrict__ cur2) {
    const int* cnt = (blockIdx.x == 0) ? cnt1 : cnt2;
    int* rs  = (blockIdx.x == 0) ? rs1  : rs2;
    int* cur = (blockIdx.x == 0) ? cur1 : cur2;
    int T    = (blockIdx.x == 0) ? T1N  : T2N;
    __shared__ int wsum[16];
    int tid = threadIdx.x;
    int lane = tid & 63, wid = tid >> 6;
    int carry = 0;
    for (int base = 0; base < T; base += 4096) {
        int i = base + tid * 4;
        int4 v = make_int4(0, 0, 0, 0);
        if (i + 3 < T) v = *(const int4*)(cnt + i);
        else {
            if (i     < T) v.x = cnt[i];
            if (i + 1 < T) v.y = cnt[i + 1];
            if (i + 2 < T) v.z = cnt[i + 2];
        }
        int tsum = v.x + v.y + v.z + v.w;
        int s = tsum;
        #pragma unroll
        for (int off = 1; off < 64; off <<= 1) {
            int t = __shfl_up(s, off, 64);
            if (lane >= off) s += t;
        }
        if (lane == 63) wsum[wid] = s;
        __syncthreads();
        if (wid == 0) {
            int w = (lane < 16) ? wsum[lane] : 0;
            #pragma unroll
            for (int off = 1; off < 16; off <<= 1) {
                int t = __shfl_up(w, off, 64);
                if (lane >= off) w += t;
            }
            if (lane < 16) wsum[lane] = w;
        }
        __syncthreads();
        int e0 = s - tsum + (wid > 0 ? wsum[wid - 1] : 0) + carry;
        int e1 = e0 + v.x, e2 = e1 + v.y, e3 = e2 + v.z;
        if (i + 3 < T) {
            *(int4*)(rs + i)  = make_int4(e0, e1, e2, e3);
            *(int4*)(cur + i) = make_int4(e0, e1, e2, e3);
        } else {
            if (i     < T) { rs[i]     = e0; cur[i]     = e0; }
            if (i + 1 < T) { rs[i + 1] = e1; cur[i + 1] = e1; }
            if (i + 2 < T) { rs[i + 2] = e2; cur[i + 2] = e2; }
        }
        int total = wsum[15];
        __syncthreads();
        carry += total;
    }
    if (tid == 0) rs[T] = carry;
}

__global__ void scatter_both(const int* __restrict__ src1, const int* __restrict__ dst1,
        const int* __restrict__ src2, const int* __restrict__ dst2,
        int* __restrict__ cur1, int* __restrict__ cur2,
        int* __restrict__ ss1, int* __restrict__ ss2, int E1, int E2) {
    int i = blockIdx.x * blockDim.x + threadIdx.x;
    int stride = gridDim.x * blockDim.x;
    int tot = E1 + E2;
    for (; i < tot; i += stride) {
        if (i < E1) {
            int pos = atomicAdd(&cur1[dst1[i]], 1);
            ss1[pos] = src1[i];
        } else {
            int j = i - E1;
            int pos = atomicAdd(&cur2[dst2[j]], 1);
            ss2[pos] = src2[j];
        }
    }
}

// ---------------------------------------------------------------------------
// Conversions
// ---------------------------------------------------------------------------
__global__ void convert_x_full(const float* __restrict__ x, short* __restrict__ xbf, long n8) {
    long i = ((long)blockIdx.x * blockDim.x + threadIdx.x);
    if (i >= n8) return;
    const float* p = x + i * 8;
    float4 v0 = *(const float4*)p;
    float4 v1 = *(const float4*)(p + 4);
    bf16x8 o;
    o[0] = f2bf(v0.x); o[1] = f2bf(v0.y); o[2] = f2bf(v0.z); o[3] = f2bf(v0.w);
    o[4] = f2bf(v1.x); o[5] = f2bf(v1.y); o[6] = f2bf(v1.z); o[7] = f2bf(v1.w);
    *(bf16x8*)(xbf + i * 8) = o;
}

// Wl1bf[256][512], Wr1bf[256][512], Wl2pad[32][256] (rows>=20 zero)
__global__ void convert_w_all(const float* __restrict__ Wl1, const float* __restrict__ Wr1,
        const float* __restrict__ Wl2, short* __restrict__ Wl1bf,
        short* __restrict__ Wr1bf, short* __restrict__ Wl2pad) {
    int i = (blockIdx.x * blockDim.x + threadIdx.x) * 8;   // element index
    const int S1 = FHID * FIN;        // 131072
    if (i < S1) {
        const float* sp = Wl1 + i;
        float4 v0 = *(const float4*)sp, v1 = *(const float4*)(sp + 4);
        bf16x8 o;
        o[0]=f2bf(v0.x); o[1]=f2bf(v0.y); o[2]=f2bf(v0.z); o[3]=f2bf(v0.w);
        o[4]=f2bf(v1.x); o[5]=f2bf(v1.y); o[6]=f2bf(v1.z); o[7]=f2bf(v1.w);
        *(bf16x8*)(Wl1bf + i) = o;
    } else if (i < 2 * S1) {
        const float* sp = Wr1 + (i - S1);
        float4 v0 = *(const float4*)sp, v1 = *(const float4*)(sp + 4);
        bf16x8 o;
        o[0]=f2bf(v0.x); o[1]=f2bf(v0.y); o[2]=f2bf(v0.z); o[3]=f2bf(v0.w);
        o[4]=f2bf(v1.x); o[5]=f2bf(v1.y); o[6]=f2bf(v1.z); o[7]=f2bf(v1.w);
        *(bf16x8*)(Wr1bf + (i - S1)) = o;
    } else if (i < 2 * S1 + NPAD * FHID) {
        int k = i - 2 * S1;           // 0..8191
        int row = k >> 8;             // 0..31
        bf16x8 o;
        if (row < FOUT) {
            const float* sp = Wl2 + (size_t)row * FHID + (k & 255);
            float4 v0 = *(const float4*)sp, v1 = *(const float4*)(sp + 4);
            o[0]=f2bf(v0.x); o[1]=f2bf(v0.y); o[2]=f2bf(v0.z); o[3]=f2bf(v0.w);
            o[4]=f2bf(v1.x); o[5]=f2bf(v1.y); o[6]=f2bf(v1.z); o[7]=f2bf(v1.w);
        } else {
            o = (bf16x8)(short)0;
        }
        *(bf16x8*)(Wl2pad + k) = o;
    }
}

// ---------------------------------------------------------------------------
// Generic bf16 MFMA GEMM: out[M,256] = A[M,512] @ W[256,512]^T
// BM=128, BN=256 (single col-block), BK=32, 4 waves (2x2 -> wave 64x128).
// global_load_lds both sides, double-buffered, slot-XOR swizzle.
// MODE 0: store bf16, no bias (y). MODE 1: store fp32 + bias (hr).
// ---------------------------------------------------------------------------
template <int MODE>
__global__ __launch_bounds__(256, 2) void gemm_l1(
        const short* __restrict__ A, const short* __restrict__ W,
        const float* __restrict__ bias, void* __restrict__ outv, int M) {
    __shared__ short As[2][128 * 32];   // 8KB each
    __shared__ short Bs[2][256 * 32];   // 16KB each
    int tid = threadIdx.x;
    int wid = tid >> 6, lane = tid & 63;
    int brow = blockIdx.x * 128;
    int wr = (wid >> 1) * 64, wc = (wid & 1) * 128;

    f32x4 acc[4][8] = {};
    int kgrp = lane >> 4;
    int r16 = lane & 15;

    auto stage = [&](int buf, int kt) {
        #pragma unroll
        for (int c2 = 0; c2 < 2; ++c2) {          // A: 8 chunks of 1KB
            int q = wid + c2 * 4;
            int c = q * 64 + lane;                // 16B chunk 0..511
            int row = c >> 2;                     // 0..127
            int sl = (c & 3) ^ ((row ^ (row >> 2)) & 3);
            int gr = brow + row; if (gr > M - 1) gr = M - 1;
            gload16(A + (size_t)gr * 512 + kt + sl * 8, (char*)As[buf] + q * 1024);
        }
        #pragma unroll
        for (int c2 = 0; c2 < 4; ++c2) {          // B: 16 chunks of 1KB
            int q = wid + c2 * 4;
            int c = q * 64 + lane;                // 0..1023
            int row = c >> 2;                     // 0..255
            int sl = (c & 3) ^ ((row ^ (row >> 2)) & 3);
            gload16(W + (size_t)row * 512 + kt + sl * 8, (char*)Bs[buf] + q * 1024);
        }
    };

    stage(0, 0);
    __syncthreads();

    int cur = 0;
    for (int kt = 0; kt < 512; kt += 32) {
        if (kt + 32 < 512) stage(cur ^ 1, kt + 32);

        bf16x8 af[4], bfr[8];
        #pragma unroll
        for (int m = 0; m < 4; ++m) {
            int row = wr + m * 16 + r16;
            int sl = kgrp ^ ((row ^ (row >> 2)) & 3);
            af[m] = *(const bf16x8*)((const char*)As[cur] + row * 64 + sl * 16);
        }
        #pragma unroll
        for (int n = 0; n < 8; ++n) {
            int row = wc + n * 16 + r16;
            int sl = kgrp ^ ((row ^ (row >> 2)) & 3);
            bfr[n] = *(const bf16x8*)((const char*)Bs[cur] + row * 64 + sl * 16);
        }
        #pragma unroll
        for (int m = 0; m < 4; ++m)
            #pragma unroll
            for (int n = 0; n < 8; ++n)
                acc[m][n] = __builtin_amdgcn_mfma_f32_16x16x32_bf16(
                        af[m], bfr[n], acc[m][n], 0, 0, 0);

        __syncthreads();
        cur ^= 1;
    }

    // epilogue: C/D layout col=lane&15, row=(lane>>4)*4+reg  [m89]
    int g4 = lane >> 4;
    #pragma unroll
    for (int n = 0; n < 8; ++n) {
        int col = wc + n * 16 + r16;
        float bv = (MODE == 1) ? bias[col] : 0.f;
        #pragma unroll
        for (int m = 0; m < 4; ++m) {
            #pragma unroll
            for (int r = 0; r < 4; ++r) {
                int row = brow + wr + m * 16 + g4 * 4 + r;
                if (row < M) {
                    if (MODE == 0)
                        ((short*)outv)[(size_t)row * 256 + col] = f2bf(acc[m][n][r]);
                    else
                        ((float*)outv)[(size_t)row * 256 + col] = acc[m][n][r] + bv;
                }
            }
        }
    }
}

// ---------------------------------------------------------------------------
// agg1: h[t] = relu( mean_j y[ss[j]] + hr[t] ),  h fp32 + hbf bf16
// one wave per target; 4 cols/lane.
// ---------------------------------------------------------------------------
__global__ void agg1_kernel(const short* __restrict__ y, const int* __restrict__ ss,
        const int* __restrict__ rs, const float* __restrict__ hr,
        float* __restrict__ h, short* __restrict__ hbf, int T) {
    int gw = (int)((blockIdx.x * (size_t)blockDim.x + threadIdx.x) >> 6);
    int lane = threadIdx.x & 63;
    if (gw >= T) return;
    int j0 = rs[gw], j1 = rs[gw + 1];
    float a[4] = {};
    for (int j = j0; j < j1; ++j) {
        int s = ss[j];
        bf16x4 v = *(const bf16x4*)(y + (size_t)s * FHID + lane * 4);
        a[0] += bf2f(v[0]); a[1] += bf2f(v[1]); a[2] += bf2f(v[2]); a[3] += bf2f(v[3]);
    }
    int d = j1 - j0;
    float inv = 1.0f / (float)(d > 1 ? d : 1);
    float4 hv = *(const float4*)(hr + (size_t)gw * FHID + lane * 4);
    float o0 = fmaxf(a[0] * inv + hv.x, 0.f);
    float o1 = fmaxf(a[1] * inv + hv.y, 0.f);
    float o2 = fmaxf(a[2] * inv + hv.z, 0.f);
    float o3 = fmaxf(a[3] * inv + hv.w, 0.f);
    *(float4*)(h + (size_t)gw * FHID + lane * 4) = make_float4(o0, o1, o2, o3);
    bf16x4 ob; ob[0] = f2bf(o0); ob[1] = f2bf(o1); ob[2] = f2bf(o2); ob[3] = f2bf(o3);
    *(bf16x4*)(hbf + (size_t)gw * FHID + lane * 4) = ob;
}

// ---------------------------------------------------------------------------
// gemmZ: z[30000,32] = hbf[30000,256] @ Wl2pad[32,256]^T   (fp32 out)
// 128 threads (2 waves), tile 128x32, BK=32, dbuf.
// ---------------------------------------------------------------------------
__global__ __launch_bounds__(128, 2) void gemm_z(
        const short* __restrict__ A, const short* __restrict__ W,
        float* __restrict__ z, int M) {
    __shared__ short As[2][128 * 32];   // 8KB
    __shared__ short Bs[2][32 * 32];    // 2KB
    int tid = threadIdx.x;
    int wid = tid >> 6, lane = tid & 63;
    int brow = blockIdx.x * 128;
    int wr = wid * 64;

    f32x4 acc[4][2] = {};
    int kgrp = lane >> 4;
    int r16 = lane & 15;

    auto stage = [&](int buf, int kt) {
        #pragma unroll
        for (int c2 = 0; c2 < 4; ++c2) {          // A: 8 chunks
            int q = wid + c2 * 2;
            int c = q * 64 + lane;
            int row = c >> 2;
            int sl = (c & 3) ^ ((row ^ (row >> 2)) & 3);
            int gr = brow + row; if (gr > M - 1) gr = M - 1;
            gload16(A + (size_t)gr * 256 + kt + sl * 8, (char*)As[buf] + q * 1024);
        }
        {                                          // B: 2 chunks (both waves)
            int q = wid;
            int c = q * 64 + lane;                // 0..127
            int row = c >> 2;                     // 0..31
            int sl = (c & 3) ^ ((row ^ (row >> 2)) & 3);
            gload16(W + (size_t)row * 256 + kt + sl * 8, (char*)Bs[buf] + q * 1024);
        }
    };

    stage(0, 0);
    __syncthreads();

    int cur = 0;
    for (int kt = 0; kt < 256; kt += 32) {
        if (kt + 32 < 256) stage(cur ^ 1, kt + 32);

        bf16x8 af[4], bfr[2];
        #pragma unroll
        for (int m = 0; m < 4; ++m) {
            int row = wr + m * 16 + r16;
            int sl = kgrp ^ ((row ^ (row >> 2)) & 3);
            af[m] = *(const bf16x8*)((const char*)As[cur] + row * 64 + sl * 16);
        }
        #pragma unroll
        for (int n = 0; n < 2; ++n) {
            int row = n * 16 + r16;
            int sl = kgrp ^ ((row ^ (row >> 2)) & 3);
            bfr[n] = *(const bf16x8*)((const char*)Bs[cur] + row * 64 + sl * 16);
        }
        #pragma unroll
        for (int m = 0; m < 4; ++m)
            #pragma unroll
            for (int n = 0; n < 2; ++n)
                acc[m][n] = __builtin_amdgcn_mfma_f32_16x16x32_bf16(
                        af[m], bfr[n], acc[m][n], 0, 0, 0);

        __syncthreads();
        cur ^= 1;
    }

    int g4 = lane >> 4;
    #pragma unroll
    for (int n = 0; n < 2; ++n) {
        int col = n * 16 + r16;
        #pragma unroll
        for (int m = 0; m < 4; ++m) {
            #pragma unroll
            for (int r = 0; r < 4; ++r) {
                int row = brow + wr + m * 16 + g4 * 4 + r;
                if (row < M)
                    z[(size_t)row * NPAD + col] = acc[m][n][r];
            }
        }
    }
}

// ---------------------------------------------------------------------------
// agg2z: mean_z[t][c] = mean_j z[ss[j]][c]   (2 targets per wave, c=lane&31)
// ---------------------------------------------------------------------------
__global__ void agg2z_kernel(const float* __restrict__ z, const int* __restrict__ ss,
        const int* __restrict__ rs, float* __restrict__ mz, int T) {
    int gw = (int)((blockIdx.x * (size_t)blockDim.x + threadIdx.x) >> 6);
    int lane = threadIdx.x & 63;
    int t = gw * 2 + (lane >> 5);
    int c = lane & 31;
    if (t >= T) return;
    int j0 = rs[t], j1 = rs[t + 1];
    float a = 0.f;
    for (int j = j0; j < j1; ++j)
        a += z[(size_t)ss[j] * NPAD + c];
    int d = j1 - j0;
    mz[(size_t)t * NPAD + c] = a / (float)(d > 1 ? d : 1);
}

// ---------------------------------------------------------------------------
// Final: out[row] = log_softmax( mean_z[row] + h[row] @ Wr2^T + bl2 )
// one wave per row; Wr2 staged in LDS.
// ---------------------------------------------------------------------------
__global__ __launch_bounds__(256) void lsm_kernel(const float* __restrict__ mz,
        const float* __restrict__ h, const float* __restrict__ Wr,
        const float* __restrict__ bias, float* __restrict__ out) {
    __shared__ float Wrs[FOUT * FHID];
    int tid = threadIdx.x;
    for (int i = tid; i < FOUT * FHID / 4; i += 256)
        ((float4*)Wrs)[i] = ((const float4*)Wr)[i];
    __syncthreads();

    int row = blockIdx.x * 4 + (tid >> 6);
    int lane = tid & 63;
    if (row >= T2N) return;

    float acc[FOUT];
    #pragma unroll
    for (int o = 0; o < FOUT; ++o) acc[o] = 0.f;

    const float* hrow = h + (size_t)row * FHID;
    #pragma unroll
    for (int kk = 0; kk < 4; ++kk) {
        int k = lane + kk * 64;
        float hv = hrow[k];
        #pragma unroll
        for (int o = 0; o < FOUT; ++o)
            acc[o] = fmaf(hv, Wrs[o * FHID + k], acc[o]);
    }
    #pragma unroll
    for (int o = 0; o < FOUT; ++o)
        #pragma unroll
        for (int off = 32; off > 0; off >>= 1)
            acc[o] += __shfl_down(acc[o], off, 64);

    if (lane == 0) {
        float mx = -1e30f;
        #pragma unroll
        for (int o = 0; o < FOUT; ++o) {
            acc[o] += mz[(size_t)row * NPAD + o] + bias[o];
            mx = fmaxf(mx, acc[o]);
        }
        float s = 0.f;
        #pragma unroll
        for (int o = 0; o < FOUT; ++o) s += expf(acc[o] - mx);
        float lse = mx + logf(s);
        float* op = out + (size_t)row * FOUT;
        #pragma unroll
        for (int o = 0; o < FOUT; ++o) op[o] = acc[o] - lse;
    }
}

// ---------------------------------------------------------------------------
extern "C" void kernel_launch(void* const* d_in, const int* in_sizes, int n_in,
                              void* d_out, int out_size, void* d_ws, size_t ws_size,
                              hipStream_t stream) {
    const float* x   = (const float*)d_in[0];
    const int* src1  = (const int*)d_in[1];
    const int* dst1  = (const int*)d_in[2];
    const int* src2  = (const int*)d_in[3];
    const int* dst2  = (const int*)d_in[4];
    const float* Wl1 = (const float*)d_in[5];
    const float* bl1 = (const float*)d_in[6];
    const float* Wr1 = (const float*)d_in[7];
    const float* Wl2 = (const float*)d_in[8];
    const float* bl2 = (const float*)d_in[9];
    const float* Wr2 = (const float*)d_in[10];
    int E1 = in_sizes[1];
    int E2 = in_sizes[3];
    int N  = in_sizes[0] / FIN;   // 150000

    char* p = (char*)d_ws;
    auto alloc = [&](size_t bytes) {
        char* r = p;
        p += (bytes + 255) & ~(size_t)255;
        return r;
    };
    short* xbf    = (short*)alloc((size_t)N * FIN * 2);      // 154 MB
    short* ybuf   = (short*)alloc((size_t)N * FHID * 2);     // 77 MB  (bf16)
    float* hr     = (float*)alloc((size_t)T1N * FHID * 4);   // 31 MB
    float* hbuf   = (float*)alloc((size_t)T1N * FHID * 4);   // 31 MB
    short* hbf    = (short*)alloc((size_t)T1N * FHID * 2);   // 15 MB
    float* zbuf   = (float*)alloc((size_t)T1N * NPAD * 4);   // 3.8 MB
    float* mz     = (float*)alloc((size_t)T2N * NPAD * 4);   // 1 MB
    short* Wl1bf  = (short*)alloc((size_t)FHID * FIN * 2);
    short* Wr1bf  = (short*)alloc((size_t)FHID * FIN * 2);
    short* Wl2pad = (short*)alloc((size_t)NPAD * FHID * 2);
    int* cnt1 = (int*)alloc((size_t)T1N * 4);
    int* cnt2 = (int*)alloc((size_t)T2N * 4);                // contiguous w/ cnt1
    int* rs1  = (int*)alloc((size_t)(T1N + 1) * 4);
    int* cur1 = (int*)alloc((size_t)T1N * 4);
    int* ss1  = (int*)alloc((size_t)E1 * 4);
    int* rs2  = (int*)alloc((size_t)(T2N + 1) * 4);
    int* cur2 = (int*)alloc((size_t)T2N * 4);
    int* ss2  = (int*)alloc((size_t)E2 * 4);

    // one memset covers cnt1+cnt2 (contiguous)
    hipMemsetAsync(cnt1, 0, (size_t)((char*)(cnt2 + T2N) - (char*)cnt1), stream);

    // CSR build first (touches ~7 MB; keeps convert->gemm->agg chain cache-warm)
    count_both<<<768, 256, 0, stream>>>(dst1, dst2, cnt1, cnt2, E1, E2);
    scan_both<<<2, 1024, 0, stream>>>(cnt1, rs1, cur1, cnt2, rs2, cur2);
    scatter_both<<<768, 256, 0, stream>>>(src1, dst1, src2, dst2, cur1, cur2, ss1, ss2, E1, E2);

    // conversions
    convert_w_all<<<((2 * FHID * FIN + NPAD * FHID) / 8 + 255) / 256, 256, 0, stream>>>(
        Wl1, Wr1, Wl2, Wl1bf, Wr1bf, Wl2pad);
    long n8 = (long)N * FIN / 8;
    convert_x_full<<<(int)((n8 + 255) / 256), 256, 0, stream>>>(x, xbf, n8);

    // layer 1: GEMM-first, then aggregate. hr-GEMM before y-GEMM so ybuf is
    // L3-hot when agg1 gathers it.
    gemm_l1<1><<<(T1N + 127) / 128, 256, 0, stream>>>(xbf, Wr1bf, bl1, hr, T1N);
    gemm_l1<0><<<(N + 127) / 128, 256, 0, stream>>>(xbf, Wl1bf, nullptr, ybuf, N);
    agg1_kernel<<<(T1N * 64 + 255) / 256, 256, 0, stream>>>(ybuf, ss1, rs1, hr, hbuf, hbf, T1N);

    // layer 2: GEMM-first (z = h @ Wl2^T), then aggregate z, then fuse rest
    gemm_z<<<(T1N + 127) / 128, 128, 0, stream>>>(hbf, Wl2pad, zbuf, T1N);
    agg2z_kernel<<<(T2N / 2 * 64 + 255) / 256, 256, 0, stream>>>(zbuf, ss2, rs2, mz, T2N);
    lsm_kernel<<<T2N / 4, 256, 0, stream>>>(mz, hbuf, Wr2, bl2, (float*)d_out);
}

// Round 9
// 659.038 us; speedup vs baseline: 1.1051x; 1.1051x over previous
//
#include <hip/hip_runtime.h>
#include <math.h>

// Problem constants (match reference)
constexpr int T1N  = 30000;
constexpr int T2N  = 8192;
constexpr int FIN  = 512;
constexpr int FHID = 256;
constexpr int FOUT = 20;
constexpr int NPAD = 32;    // z / mean_z column stride (20 padded to 32)

typedef short bf16x8 __attribute__((ext_vector_type(8)));
typedef short bf16x4 __attribute__((ext_vector_type(4)));
typedef float f32x4  __attribute__((ext_vector_type(4)));

__device__ __forceinline__ short f2bf(float f) {
    unsigned u = __float_as_uint(f);
    u += 0x7fff + ((u >> 16) & 1);     // RNE; inputs are finite normals
    return (short)(u >> 16);
}
__device__ __forceinline__ float bf2f(short s) {
    return __uint_as_float(((unsigned)(unsigned short)s) << 16);
}

__device__ __forceinline__ void gload16(const void* g, void* l) {
    __builtin_amdgcn_global_load_lds(
        (const __attribute__((address_space(1))) void*)g,
        (__attribute__((address_space(3))) void*)l, 16, 0, 0);
}

// ---------------------------------------------------------------------------
// CSR build (both graphs in merged dispatches)
// ---------------------------------------------------------------------------
__global__ void count_both(const int* __restrict__ dst1, const int* __restrict__ dst2,
        int* __restrict__ cnt1, int* __restrict__ cnt2, int E1, int E2) {
    int i = blockIdx.x * blockDim.x + threadIdx.x;
    int stride = gridDim.x * blockDim.x;
    int tot = E1 + E2;
    for (; i < tot; i += stride) {
        if (i < E1) atomicAdd(&cnt1[dst1[i]], 1);
        else        atomicAdd(&cnt2[dst2[i - E1]], 1);
    }
}

// grid=2: block 0 scans graph1, block 1 scans graph2. int4 (4096/chunk).
__global__ __launch_bounds__(1024) void scan_both(
        const int* __restrict__ cnt1, int* __restrict__ rs1, int* __restrict__ cur1,
        const int* __restrict__ cnt2, int* __restrict__ rs2, int* __restrict__ cur2) {
    const int* cnt = (blockIdx.x == 0) ? cnt1 : cnt2;
    int* rs  = (blockIdx.x == 0) ? rs1  : rs2;
    int* cur = (blockIdx.x == 0) ? cur1 : cur2;
    int T    = (blockIdx.x == 0) ? T1N  : T2N;
    __shared__ int wsum[16];
    int tid = threadIdx.x;
    int lane = tid & 63, wid = tid >> 6;
    int carry = 0;
    for (int base = 0; base < T; base += 4096) {
        int i = base + tid * 4;
        int4 v = make_int4(0, 0, 0, 0);
        if (i + 3 < T) v = *(const int4*)(cnt + i);
        else {
            if (i     < T) v.x = cnt[i];
            if (i + 1 < T) v.y = cnt[i + 1];
            if (i + 2 < T) v.z = cnt[i + 2];
        }
        int tsum = v.x + v.y + v.z + v.w;
        int s = tsum;
        #pragma unroll
        for (int off = 1; off < 64; off <<= 1) {
            int t = __shfl_up(s, off, 64);
            if (lane >= off) s += t;
        }
        if (lane == 63) wsum[wid] = s;
        __syncthreads();
        if (wid == 0) {
            int w = (lane < 16) ? wsum[lane] : 0;
            #pragma unroll
            for (int off = 1; off < 16; off <<= 1) {
                int t = __shfl_up(w, off, 64);
                if (lane >= off) w += t;
            }
            if (lane < 16) wsum[lane] = w;
        }
        __syncthreads();
        int e0 = s - tsum + (wid > 0 ? wsum[wid - 1] : 0) + carry;
        int e1 = e0 + v.x, e2 = e1 + v.y, e3 = e2 + v.z;
        if (i + 3 < T) {
            *(int4*)(rs + i)  = make_int4(e0, e1, e2, e3);
            *(int4*)(cur + i) = make_int4(e0, e1, e2, e3);
        } else {
            if (i     < T) { rs[i]     = e0; cur[i]     = e0; }
            if (i + 1 < T) { rs[i + 1] = e1; cur[i + 1] = e1; }
            if (i + 2 < T) { rs[i + 2] = e2; cur[i + 2] = e2; }
        }
        int total = wsum[15];
        __syncthreads();
        carry += total;
    }
    if (tid == 0) rs[T] = carry;
}

__global__ void scatter_both(const int* __restrict__ src1, const int* __restrict__ dst1,
        const int* __restrict__ src2, const int* __restrict__ dst2,
        int* __restrict__ cur1, int* __restrict__ cur2,
        int* __restrict__ ss1, int* __restrict__ ss2, int E1, int E2) {
    int i = blockIdx.x * blockDim.x + threadIdx.x;
    int stride = gridDim.x * blockDim.x;
    int tot = E1 + E2;
    for (; i < tot; i += stride) {
        if (i < E1) {
            int pos = atomicAdd(&cur1[dst1[i]], 1);
            ss1[pos] = src1[i];
        } else {
            int j = i - E1;
            int pos = atomicAdd(&cur2[dst2[j]], 1);
            ss2[pos] = src2[j];
        }
    }
}

// ---------------------------------------------------------------------------
// Conversions
// ---------------------------------------------------------------------------
__global__ void convert_x_full(const float* __restrict__ x, short* __restrict__ xbf, long n8) {
    long i = ((long)blockIdx.x * blockDim.x + threadIdx.x);
    if (i >= n8) return;
    const float* p = x + i * 8;
    float4 v0 = *(const float4*)p;
    float4 v1 = *(const float4*)(p + 4);
    bf16x8 o;
    o[0] = f2bf(v0.x); o[1] = f2bf(v0.y); o[2] = f2bf(v0.z); o[3] = f2bf(v0.w);
    o[4] = f2bf(v1.x); o[5] = f2bf(v1.y); o[6] = f2bf(v1.z); o[7] = f2bf(v1.w);
    *(bf16x8*)(xbf + i * 8) = o;
}

// Wcat[256][1024] = [Wl1 | Wr1] bf16 ; Wl2pad[32][256] (rows>=20 zero)
__global__ void convert_w_all(const float* __restrict__ Wl1, const float* __restrict__ Wr1,
        const float* __restrict__ Wl2, short* __restrict__ Wcat,
        short* __restrict__ Wl2pad) {
    int i = (blockIdx.x * blockDim.x + threadIdx.x) * 8;   // element index
    const int SC = FHID * 1024;        // 262144 (Wcat elements)
    if (i < SC) {
        int n = i >> 10;
        int k = i & 1023;
        const float* sp = (k < 512) ? (Wl1 + (size_t)n * FIN + k)
                                    : (Wr1 + (size_t)n * FIN + (k - 512));
        float4 v0 = *(const float4*)sp, v1 = *(const float4*)(sp + 4);
        bf16x8 o;
        o[0]=f2bf(v0.x); o[1]=f2bf(v0.y); o[2]=f2bf(v0.z); o[3]=f2bf(v0.w);
        o[4]=f2bf(v1.x); o[5]=f2bf(v1.y); o[6]=f2bf(v1.z); o[7]=f2bf(v1.w);
        *(bf16x8*)(Wcat + i) = o;
    } else if (i < SC + NPAD * FHID) {
        int k = i - SC;               // 0..8191
        int row = k >> 8;             // 0..31
        bf16x8 o;
        if (row < FOUT) {
            const float* sp = Wl2 + (size_t)row * FHID + (k & 255);
            float4 v0 = *(const float4*)sp, v1 = *(const float4*)(sp + 4);
            o[0]=f2bf(v0.x); o[1]=f2bf(v0.y); o[2]=f2bf(v0.z); o[3]=f2bf(v0.w);
            o[4]=f2bf(v1.x); o[5]=f2bf(v1.y); o[6]=f2bf(v1.z); o[7]=f2bf(v1.w);
        } else {
            o = (bf16x8)(short)0;
        }
        *(bf16x8*)(Wl2pad + k) = o;
    }
}

// ---------------------------------------------------------------------------
// agg1: meanbf[t] = mean_j xbf[ss[j]]  (bf16 rows of 512; fp32 accum)
// one wave per target, 8 bf16/lane; 2-edge unrolled for load ILP.
// ---------------------------------------------------------------------------
__global__ void agg1_kernel(const short* __restrict__ xbf, const int* __restrict__ ss,
        const int* __restrict__ rs, short* __restrict__ meanbf, int T) {
    int gw = (int)((blockIdx.x * (size_t)blockDim.x + threadIdx.x) >> 6);
    int lane = threadIdx.x & 63;
    if (gw >= T) return;
    int j0 = rs[gw], j1 = rs[gw + 1];
    float a[8] = {};
    int j = j0;
    for (; j + 1 < j1; j += 2) {
        int s0 = ss[j], s1 = ss[j + 1];
        bf16x8 v0 = *(const bf16x8*)(xbf + (size_t)s0 * FIN + lane * 8);
        bf16x8 v1 = *(const bf16x8*)(xbf + (size_t)s1 * FIN + lane * 8);
        #pragma unroll
        for (int q = 0; q < 8; ++q) a[q] += bf2f(v0[q]) + bf2f(v1[q]);
    }
    if (j < j1) {
        int s0 = ss[j];
        bf16x8 v0 = *(const bf16x8*)(xbf + (size_t)s0 * FIN + lane * 8);
        #pragma unroll
        for (int q = 0; q < 8; ++q) a[q] += bf2f(v0[q]);
    }
    int d = j1 - j0;
    float inv = 1.0f / (float)(d > 1 ? d : 1);
    bf16x8 o;
    #pragma unroll
    for (int q = 0; q < 8; ++q) o[q] = f2bf(a[q] * inv);
    *(bf16x8*)(meanbf + (size_t)gw * FIN + lane * 8) = o;
}

// ---------------------------------------------------------------------------
// GEMM1 (bf16 MFMA): h[30000,256] = relu([mean|x] @ [Wl1|Wr1]^T + bl1)
// A-halves from meanbf / xbf (row stride 512); W = Wcat (stride 1024).
// 128x128 tile, BK=32, 4 waves (2x2), double-buffered LDS, slot-XOR swizzle.
// Epilogue writes h fp32 AND hbf bf16 (feeds lsm and gemm_z).
// ---------------------------------------------------------------------------
__global__ __launch_bounds__(256, 2) void gemm1_mfma(
        const short* __restrict__ Am, const short* __restrict__ Ax,
        const short* __restrict__ W, const float* __restrict__ bias,
        float* __restrict__ h, short* __restrict__ hbf) {
    __shared__ short As[2][128 * 32];   // 8KB each
    __shared__ short Bs[2][128 * 32];
    int tid = threadIdx.x;
    int wid = tid >> 6, lane = tid & 63;
    int brow = blockIdx.x * 128, bcol = blockIdx.y * 128;
    int wr = (wid >> 1) * 64, wc = (wid & 1) * 64;

    f32x4 acc[4][4] = {};
    int kgrp = lane >> 4;
    int r16 = lane & 15;

    auto stage = [&](int buf, int kt) {
        const short* Abase = (kt < 512) ? Am : Ax;
        int ko = kt & 511;
        #pragma unroll
        for (int c2 = 0; c2 < 2; ++c2) {
            int q = wid + c2 * 4;            // 1KB chunk 0..7
            int c = q * 64 + lane;           // 16B chunk 0..511
            int row = c >> 2;                // 0..127
            int rx = (row ^ (row >> 2)) & 3;
            int sl = (c & 3) ^ rx;           // pre-swizzled global slot
            int gr = brow + row; if (gr > T1N - 1) gr = T1N - 1;
            gload16(Abase + (size_t)gr * 512 + ko + sl * 8, (char*)As[buf] + q * 1024);
            gload16(W + (size_t)(bcol + row) * 1024 + kt + sl * 8, (char*)Bs[buf] + q * 1024);
        }
    };

    stage(0, 0);
    __syncthreads();

    int cur = 0;
    for (int kt = 0; kt < 1024; kt += 32) {
        if (kt + 32 < 1024) stage(cur ^ 1, kt + 32);

        bf16x8 af[4], bfr[4];
        #pragma unroll
        for (int m = 0; m < 4; ++m) {
            int row = wr + m * 16 + r16;
            int sl = kgrp ^ ((row ^ (row >> 2)) & 3);
            af[m] = *(const bf16x8*)((const char*)As[cur] + row * 64 + sl * 16);
        }
        #pragma unroll
        for (int n = 0; n < 4; ++n) {
            int row = wc + n * 16 + r16;
            int sl = kgrp ^ ((row ^ (row >> 2)) & 3);
            bfr[n] = *(const bf16x8*)((const char*)Bs[cur] + row * 64 + sl * 16);
        }
        #pragma unroll
        for (int m = 0; m < 4; ++m)
            #pragma unroll
            for (int n = 0; n < 4; ++n)
                acc[m][n] = __builtin_amdgcn_mfma_f32_16x16x32_bf16(
                        af[m], bfr[n], acc[m][n], 0, 0, 0);

        __syncthreads();   // drains vmcnt (stage done) + lgkm (reads done)
        cur ^= 1;
    }

    // epilogue: C/D layout col=lane&15, row=(lane>>4)*4+reg  [m89]
    int g4 = lane >> 4;
    #pragma unroll
    for (int n = 0; n < 4; ++n) {
        int col = bcol + wc + n * 16 + r16;
        float bv = bias[col];
        #pragma unroll
        for (int m = 0; m < 4; ++m) {
            #pragma unroll
            for (int r = 0; r < 4; ++r) {
                int row = brow + wr + m * 16 + g4 * 4 + r;
                if (row < T1N) {
                    float v = acc[m][n][r] + bv;
                    v = v > 0.f ? v : 0.f;
                    h[(size_t)row * FHID + col] = v;
                    hbf[(size_t)row * FHID + col] = f2bf(v);
                }
            }
        }
    }
}

// ---------------------------------------------------------------------------
// gemmZ: z[30000,32] = hbf[30000,256] @ Wl2pad[32,256]^T   (fp32 out)
// 128 threads (2 waves), tile 128x32, BK=32, dbuf.
// ---------------------------------------------------------------------------
__global__ __launch_bounds__(128, 2) void gemm_z(
        const short* __restrict__ A, const short* __restrict__ W,
        float* __restrict__ z, int M) {
    __shared__ short As[2][128 * 32];   // 8KB
    __shared__ short Bs[2][32 * 32];    // 2KB
    int tid = threadIdx.x;
    int wid = tid >> 6, lane = tid & 63;
    int brow = blockIdx.x * 128;
    int wr = wid * 64;

    f32x4 acc[4][2] = {};
    int kgrp = lane >> 4;
    int r16 = lane & 15;

    auto stage = [&](int buf, int kt) {
        #pragma unroll
        for (int c2 = 0; c2 < 4; ++c2) {          // A: 8 chunks
            int q = wid + c2 * 2;
            int c = q * 64 + lane;
            int row = c >> 2;
            int sl = (c & 3) ^ ((row ^ (row >> 2)) & 3);
            int gr = brow + row; if (gr > M - 1) gr = M - 1;
            gload16(A + (size_t)gr * 256 + kt + sl * 8, (char*)As[buf] + q * 1024);
        }
        {                                          // B: 2 chunks (both waves)
            int q = wid;
            int c = q * 64 + lane;                // 0..127
            int row = c >> 2;                     // 0..31
            int sl = (c & 3) ^ ((row ^ (row >> 2)) & 3);
            gload16(W + (size_t)row * 256 + kt + sl * 8, (char*)Bs[buf] + q * 1024);
        }
    };

    stage(0, 0);
    __syncthreads();

    int cur = 0;
    for (int kt = 0; kt < 256; kt += 32) {
        if (kt + 32 < 256) stage(cur ^ 1, kt + 32);

        bf16x8 af[4], bfr[2];
        #pragma unroll
        for (int m = 0; m < 4; ++m) {
            int row = wr + m * 16 + r16;
            int sl = kgrp ^ ((row ^ (row >> 2)) & 3);
            af[m] = *(const bf16x8*)((const char*)As[cur] + row * 64 + sl * 16);
        }
        #pragma unroll
        for (int n = 0; n < 2; ++n) {
            int row = n * 16 + r16;
            int sl = kgrp ^ ((row ^ (row >> 2)) & 3);
            bfr[n] = *(const bf16x8*)((const char*)Bs[cur] + row * 64 + sl * 16);
        }
        #pragma unroll
        for (int m = 0; m < 4; ++m)
            #pragma unroll
            for (int n = 0; n < 2; ++n)
                acc[m][n] = __builtin_amdgcn_mfma_f32_16x16x32_bf16(
                        af[m], bfr[n], acc[m][n], 0, 0, 0);

        __syncthreads();
        cur ^= 1;
    }

    int g4 = lane >> 4;
    #pragma unroll
    for (int n = 0; n < 2; ++n) {
        int col = n * 16 + r16;
        #pragma unroll
        for (int m = 0; m < 4; ++m) {
            #pragma unroll
            for (int r = 0; r < 4; ++r) {
                int row = brow + wr + m * 16 + g4 * 4 + r;
                if (row < M)
                    z[(size_t)row * NPAD + col] = acc[m][n][r];
            }
        }
    }
}

// ---------------------------------------------------------------------------
// agg2z: mean_z[t][c] = mean_j z[ss[j]][c]   (2 targets per wave, c=lane&31)
// ---------------------------------------------------------------------------
__global__ void agg2z_kernel(const float* __restrict__ z, const int* __restrict__ ss,
        const int* __restrict__ rs, float* __restrict__ mz, int T) {
    int gw = (int)((blockIdx.x * (size_t)blockDim.x + threadIdx.x) >> 6);
    int lane = threadIdx.x & 63;
    int t = gw * 2 + (lane >> 5);
    int c = lane & 31;
    if (t >= T) return;
    int j0 = rs[t], j1 = rs[t + 1];
    float a = 0.f;
    for (int j = j0; j < j1; ++j)
        a += z[(size_t)ss[j] * NPAD + c];
    int d = j1 - j0;
    mz[(size_t)t * NPAD + c] = a / (float)(d > 1 ? d : 1);
}

// ---------------------------------------------------------------------------
// Final: out[row] = log_softmax( mean_z[row] + h[row] @ Wr2^T + bl2 )
// one wave per row; Wr2 staged in LDS.
// ---------------------------------------------------------------------------
__global__ __launch_bounds__(256) void lsm_kernel(const float* __restrict__ mz,
        const float* __restrict__ h, const float* __restrict__ Wr,
        const float* __restrict__ bias, float* __restrict__ out) {
    __shared__ float Wrs[FOUT * FHID];
    int tid = threadIdx.x;
    for (int i = tid; i < FOUT * FHID / 4; i += 256)
        ((float4*)Wrs)[i] = ((const float4*)Wr)[i];
    __syncthreads();

    int row = blockIdx.x * 4 + (tid >> 6);
    int lane = tid & 63;
    if (row >= T2N) return;

    float acc[FOUT];
    #pragma unroll
    for (int o = 0; o < FOUT; ++o) acc[o] = 0.f;

    const float* hrow = h + (size_t)row * FHID;
    #pragma unroll
    for (int kk = 0; kk < 4; ++kk) {
        int k = lane + kk * 64;
        float hv = hrow[k];
        #pragma unroll
        for (int o = 0; o < FOUT; ++o)
            acc[o] = fmaf(hv, Wrs[o * FHID + k], acc[o]);
    }
    #pragma unroll
    for (int o = 0; o < FOUT; ++o)
        #pragma unroll
        for (int off = 32; off > 0; off >>= 1)
            acc[o] += __shfl_down(acc[o], off, 64);

    if (lane == 0) {
        float mx = -1e30f;
        #pragma unroll
        for (int o = 0; o < FOUT; ++o) {
            acc[o] += mz[(size_t)row * NPAD + o] + bias[o];
            mx = fmaxf(mx, acc[o]);
        }
        float s = 0.f;
        #pragma unroll
        for (int o = 0; o < FOUT; ++o) s += expf(acc[o] - mx);
        float lse = mx + logf(s);
        float* op = out + (size_t)row * FOUT;
        #pragma unroll
        for (int o = 0; o < FOUT; ++o) op[o] = acc[o] - lse;
    }
}

// ---------------------------------------------------------------------------
extern "C" void kernel_launch(void* const* d_in, const int* in_sizes, int n_in,
                              void* d_out, int out_size, void* d_ws, size_t ws_size,
                              hipStream_t stream) {
    const float* x   = (const float*)d_in[0];
    const int* src1  = (const int*)d_in[1];
    const int* dst1  = (const int*)d_in[2];
    const int* src2  = (const int*)d_in[3];
    const int* dst2  = (const int*)d_in[4];
    const float* Wl1 = (const float*)d_in[5];
    const float* bl1 = (const float*)d_in[6];
    const float* Wr1 = (const float*)d_in[7];
    const float* Wl2 = (const float*)d_in[8];
    const float* bl2 = (const float*)d_in[9];
    const float* Wr2 = (const float*)d_in[10];
    int E1 = in_sizes[1];
    int E2 = in_sizes[3];
    int N  = in_sizes[0] / FIN;   // 150000

    char* p = (char*)d_ws;
    auto alloc = [&](size_t bytes) {
        char* r = p;
        p += (bytes + 255) & ~(size_t)255;
        return r;
    };
    short* xbf    = (short*)alloc((size_t)N * FIN * 2);      // 154 MB (L3-fit)
    short* meanbf = (short*)alloc((size_t)T1N * FIN * 2);    // 31 MB
    float* hbuf   = (float*)alloc((size_t)T1N * FHID * 4);   // 31 MB
    short* hbf    = (short*)alloc((size_t)T1N * FHID * 2);   // 15 MB
    float* zbuf   = (float*)alloc((size_t)T1N * NPAD * 4);   // 3.8 MB
    float* mz     = (float*)alloc((size_t)T2N * NPAD * 4);   // 1 MB
    short* Wcat   = (short*)alloc((size_t)FHID * 1024 * 2);  // 0.5 MB
    short* Wl2pad = (short*)alloc((size_t)NPAD * FHID * 2);
    int* cnt1 = (int*)alloc((size_t)T1N * 4);
    int* cnt2 = (int*)alloc((size_t)T2N * 4);                // contiguous w/ cnt1
    int* rs1  = (int*)alloc((size_t)(T1N + 1) * 4);
    int* cur1 = (int*)alloc((size_t)T1N * 4);
    int* ss1  = (int*)alloc((size_t)E1 * 4);
    int* rs2  = (int*)alloc((size_t)(T2N + 1) * 4);
    int* cur2 = (int*)alloc((size_t)T2N * 4);
    int* ss2  = (int*)alloc((size_t)E2 * 4);

    // one memset covers cnt1+cnt2 (contiguous)
    hipMemsetAsync(cnt1, 0, (size_t)((char*)(cnt2 + T2N) - (char*)cnt1), stream);

    // CSR build first (touches ~7 MB; keeps convert->agg->gemm chain cache-warm)
    count_both<<<768, 256, 0, stream>>>(dst1, dst2, cnt1, cnt2, E1, E2);
    scan_both<<<2, 1024, 0, stream>>>(cnt1, rs1, cur1, cnt2, rs2, cur2);
    scatter_both<<<768, 256, 0, stream>>>(src1, dst1, src2, dst2, cur1, cur2, ss1, ss2, E1, E2);

    // conversions
    convert_w_all<<<((FHID * 1024 + NPAD * FHID) / 8 + 255) / 256, 256, 0, stream>>>(
        Wl1, Wr1, Wl2, Wcat, Wl2pad);
    long n8 = (long)N * FIN / 8;
    convert_x_full<<<(int)((n8 + 255) / 256), 256, 0, stream>>>(x, xbf, n8);

    // layer 1: aggregate (xbf L3-hot), then ONE fused concat-K GEMM w/ relu
    agg1_kernel<<<(T1N * 64 + 255) / 256, 256, 0, stream>>>(xbf, ss1, rs1, meanbf, T1N);
    dim3 g1((T1N + 127) / 128, FHID / 128);
    gemm1_mfma<<<g1, 256, 0, stream>>>(meanbf, xbf, Wcat, bl1, hbuf, hbf);

    // layer 2: GEMM-first (z = h @ Wl2^T), then aggregate z, then fuse rest
    gemm_z<<<(T1N + 127) / 128, 128, 0, stream>>>(hbf, Wl2pad, zbuf, T1N);
    agg2z_kernel<<<(T2N / 2 * 64 + 255) / 256, 256, 0, stream>>>(zbuf, ss2, rs2, mz, T2N);
    lsm_kernel<<<T2N / 4, 256, 0, stream>>>(mz, hbuf, Wr2, bl2, (float*)d_out);
}